// Round 13
// baseline (322.808 us; speedup 1.0000x reference)
//
#include <hip/hip_runtime.h>
#include <math.h>

#define N_NODES 8192
#define N_EDGES 131072
#define C 32
#define Zn 10
#define NG 16
#define NB 8
#define H 64
#define TABN 4096
#define TPP 16     // table points per block (16 threads per point)
#define NPB 8      // nodes per node_kernel block (1 wave per node)
#define CAP 64     // bucket capacity per node
#define SL 48      // max edges processed per node

// prep block map
#define TB_TAB  514   // 2 * 257 table blocks (first: longest job)
#define TB_EDGE (TB_TAB + 512)
#define TB_H0   (TB_EDGE + 128)

__device__ __forceinline__ float silu_f(float v){ return v / (1.0f + __expf(-v)); }

// ================================================================ prep (fused):
// [0,514): radial MLP tables, 16 pts/block x 16 thr/pt
// [514,1026): edge filter + bucket snd write
// [1026,1154): species + compact h0c (1 MB) + d_out zero
__global__ __launch_bounds__(256)
void prep_kernel(const float* __restrict__ pos, const int* __restrict__ ei,
                 int* __restrict__ cursor, int* __restrict__ bucket,
                 const float* __restrict__ na, const float* __restrict__ Wemb,
                 int* __restrict__ species, float* __restrict__ h0c,
                 const float* __restrict__ R0g, const float* __restrict__ R1g,
                 const float* __restrict__ R2g, const float* __restrict__ R3g,
                 float2* __restrict__ Tab2, float* __restrict__ out){
  __shared__ float xsh[TPP*65];
  __shared__ int spec_lds[64];
  int b = blockIdx.x;
  int tid = threadIdx.x;

  if (b >= TB_TAB){
    if (b < TB_EDGE){
      // ---- edge filter + bucket
      int e = (b-TB_TAB)*256 + tid;
      int snd = ei[e], rcv = ei[N_EDGES + e];
      float px = pos[rcv*3+0]-pos[snd*3+0];
      float py = pos[rcv*3+1]-pos[snd*3+1];
      float pz = pos[rcv*3+2]-pos[snd*3+2];
      float r2 = px*px+py*py+pz*pz;
      if (r2 < 25.0f){
        int slot = atomicAdd(cursor + rcv, 1);
        if (slot < CAP) bucket[rcv*CAP + slot] = snd;
      }
    } else {
      // ---- species + compact h0
      int n0 = (b-TB_EDGE)*64;
      if (tid < 64){
        int n = n0 + tid;
        int spec = 0;
        #pragma unroll
        for (int z = 1; z < Zn; z++) if (na[n*Zn+z] > 0.5f) spec = z;
        species[n] = spec;
        spec_lds[tid] = spec;
      }
      if (b == TB_EDGE && tid >= 64 && tid < 128) out[tid-64] = 0.f;
      __syncthreads();
      float4* dst = (float4*)(h0c + (size_t)n0*32);
      #pragma unroll
      for (int it = 0; it < 2; it++){
        int f = it*256 + tid;          // [0, 512) float4s = 64 nodes x 8
        int node = f >> 3, q = f & 7;
        dst[f] = ((const float4*)(Wemb + spec_lds[node]*C))[q];
      }
    }
    return;
  }

  // ---- table part: 16 threads per point
  const int nb = 257;                // blocks per half
  int half = (b >= nb) ? 1 : 0;
  int blk  = b - half*nb;
  const float* R0i = R0g + half*NB*H;
  const float* R1i = R1g + half*H*H;
  const float* R2i = R2g + half*H*H;
  const float* R3i = R3g + half*H*96;
  float2* TabH = Tab2 + (size_t)half*((size_t)TABN*96);

  int pl = tid >> 4, jt = tid & 15;
  int i = blk*TPP + pl;
  float r = (i == 0) ? 1e-6f : (float)i * (5.0f/TABN);
  if (jt < 8){
    float xr = r*0.2f;
    float env = 0.f;
    if (xr < 1.0f){
      float x2 = xr*xr, x5 = x2*x2*xr;
      env = 1.f - 21.f*x5 + 35.f*x5*xr - 15.f*x5*x2;
    }
    float sc = 0.6324555320336759f / r * env;
    xsh[pl*65 + jt] = sc * sinf((float)(jt+1)*0.6283185307179586f*r);
  }
  __syncthreads();

  float acc[6];
  // L0: 8 -> 64, 4 cols/thread
  #pragma unroll
  for (int j = 0; j < 4; j++) acc[j] = 0.f;
  #pragma unroll
  for (int k = 0; k < 8; k++){
    float xk = xsh[pl*65 + k];
    float4 w = *(const float4*)(R0i + k*H + jt*4);
    acc[0]=fmaf(xk,w.x,acc[0]); acc[1]=fmaf(xk,w.y,acc[1]);
    acc[2]=fmaf(xk,w.z,acc[2]); acc[3]=fmaf(xk,w.w,acc[3]);
  }
  __syncthreads();
  #pragma unroll
  for (int j = 0; j < 4; j++) xsh[pl*65 + jt*4 + j] = silu_f(acc[j]);
  __syncthreads();

  const float* Wl[2] = {R1i, R2i};
  #pragma unroll
  for (int L = 0; L < 2; L++){
    const float* W = Wl[L];
    #pragma unroll
    for (int j = 0; j < 4; j++) acc[j] = 0.f;
    #pragma unroll 8
    for (int k = 0; k < H; k++){
      float xk = xsh[pl*65 + k];
      float4 w = *(const float4*)(W + k*H + jt*4);
      acc[0]=fmaf(xk,w.x,acc[0]); acc[1]=fmaf(xk,w.y,acc[1]);
      acc[2]=fmaf(xk,w.z,acc[2]); acc[3]=fmaf(xk,w.w,acc[3]);
    }
    __syncthreads();
    #pragma unroll
    for (int j = 0; j < 4; j++) xsh[pl*65 + jt*4 + j] = silu_f(acc[j]);
    __syncthreads();
  }

  // L3: 64 -> 96, 6 cols/thread
  #pragma unroll
  for (int j = 0; j < 6; j++) acc[j] = 0.f;
  #pragma unroll 8
  for (int k = 0; k < H; k++){
    float xk = xsh[pl*65 + k];
    const float* wp = R3i + k*96 + jt*6;
    float2 w0 = *(const float2*)(wp);
    float2 w1 = *(const float2*)(wp+2);
    float2 w2 = *(const float2*)(wp+4);
    acc[0]=fmaf(xk,w0.x,acc[0]); acc[1]=fmaf(xk,w0.y,acc[1]);
    acc[2]=fmaf(xk,w1.x,acc[2]); acc[3]=fmaf(xk,w1.y,acc[3]);
    acc[4]=fmaf(xk,w2.x,acc[4]); acc[5]=fmaf(xk,w2.y,acc[5]);
  }
  if (i <= TABN){
    int cb = jt*6;
    #pragma unroll
    for (int j = 0; j < 6; j++){
      int c = cb + j;
      float val = acc[j];
      if (i < TABN) TabH[(size_t)i*96 + c].x = val;      // lerp lower endpoint
      if (i > 0)    TabH[(size_t)(i-1)*96 + c].y = val;  // lerp upper endpoint
    }
  }
}

// ================================================================ node:
// lane-parallel preamble -> dependency-free gather -> global-weight mix
// -> gate -> readout.  iter0 reads compact h0c (1 MB, L2-hot); iter1 reads hg_mid.
// iter1 skips the dead hg_out write.
__global__ __launch_bounds__(512)
void node_kernel(const float2* __restrict__ Tab2, const int* __restrict__ bucket,
                 const int* __restrict__ deg, const float* __restrict__ h0c,
                 const float* __restrict__ hg_in, float* __restrict__ hg_out,
                 const float* __restrict__ Wm_g, const float* __restrict__ Ws_g,
                 const float* __restrict__ Wp1, const float* __restrict__ Wp2,
                 const float* __restrict__ Wp3,
                 const int* __restrict__ species, const int* __restrict__ batch,
                 const float* __restrict__ ae, const float* __restrict__ charges,
                 const float* __restrict__ pos,
                 const float* __restrict__ wEv, const float* __restrict__ wDv,
                 const float* __restrict__ Whg, const float* __restrict__ wE2g,
                 int iter, float* __restrict__ out){
  __shared__ float abuf[NPB][288];    // A (gather) -> A-mixed -> h_new
  __shared__ float sbuf[NPB][288];    // estage during gather -> sc after mix
  __shared__ float glds[NG][4];
  float* estage = &sbuf[0][0];        // NPB*SL*6 = 2304 = NPB*288, exact alias
  int tid = threadIdx.x;
  if (tid < NG*4) glds[tid>>2][tid&3] = 0.f;
  int w = tid >> 6, lane = tid & 63;
  int c31 = lane & 31;
  bool hi = lane >= 32;
  int ng0 = blockIdx.x*NPB;
  int n = ng0 + w;

  // ---- lane-parallel preamble: stage all edge params
  int cnt = deg[n]; if (cnt > SL) cnt = SL;
  if (lane < cnt){
    int snd = bucket[n*CAP + lane];
    float px = pos[n*3+0] - pos[snd*3+0];
    float py = pos[n*3+1] - pos[snd*3+1];
    float pz = pos[n*3+2] - pos[snd*3+2];
    float r = sqrtf(px*px+py*py+pz*pz + 1e-12f);
    float inv = 1.0f/r;
    float* es = estage + (w*SL + lane)*6;
    es[0] = px*inv; es[1] = py*inv; es[2] = pz*inv;
    es[3] = r * (TABN/5.0f);
    es[4] = __int_as_float(snd);
  }

  // ---- gather: only independent loads per edge (3 table + 1 hs)
  const float s3 = 1.7320508075688772f;
  const float s5 = 2.23606797749979f;
  const float s15 = 3.872983346207417f;
  int colA = (hi ? 32 : 0) + c31;
  int colB = 32 + c31;
  int colC = 64 + c31;
  float acc0=0.f, acc1=0.f, acc2=0.f, acc3=0.f, acc4=0.f;
  #pragma unroll 4
  for (int j = 0; j < cnt; j++){
    const float* es = estage + (w*SL + j)*6;
    float x = es[0], y = es[1], z = es[2], u = es[3];
    int snd = __float_as_int(es[4]);
    int i0 = (int)u;
    if (i0 > TABN-1) i0 = TABN-1;
    float f = u - (float)i0;
    const float2* T2 = Tab2 + (size_t)i0*96;
    float hs = (iter == 0) ? h0c[(size_t)snd*32 + c31]
                           : hg_in[(size_t)snd*288 + c31];
    float2 ta = T2[colA];
    float2 tb = T2[colB];
    float2 tc = T2[colC];
    float wv0 = fmaf(ta.y - ta.x, f, ta.x) * hs;
    float wv1 = fmaf(tb.y - tb.x, f, tb.x) * hs;
    float wv2 = fmaf(tc.y - tc.x, f, tc.x) * hs;
    float Ys0 = hi ? s3*x : 1.0f;
    float Ys1 = s3 * (hi ? z : y);
    float Ys2 = s15 * (hi ? y*z : x*y);
    float Ys3 = hi ? s15*x*z : 0.5f*s5*(3.f*z*z - 1.f);
    float Ys4 = 0.5f*s15*(x*x - y*y);
    acc0 = fmaf(wv0, Ys0, acc0);
    acc1 = fmaf(wv1, Ys1, acc1);
    acc2 = fmaf(wv2, Ys2, acc2);
    acc3 = fmaf(wv2, Ys3, acc3);
    acc4 = fmaf(wv2, Ys4, acc4);
  }
  __syncthreads();                    // estage fully consumed (aliases sbuf)
  abuf[w][lane]       = acc0 * (1.0f/16.0f);
  abuf[w][lane + 64]  = acc1 * (1.0f/16.0f);
  abuf[w][lane + 128] = acc2 * (1.0f/16.0f);
  abuf[w][lane + 192] = acc3 * (1.0f/16.0f);
  if (!hi) abuf[w][lane + 256] = acc4 * (1.0f/16.0f);
  __syncthreads();

  // ---- mix: waves 0..4 each own slot w across the 8 nodes
  float a2[NPB], scv[NPB];
  int idx0 = w*64 + lane;
  bool actm = (w < 5) && (idx0 < 288);
  if (w < 5){
    int m = idx0 >> 5; if (m > 8) m = 8;
    int l = (m >= 4) ? 2 : ((m >= 1) ? 1 : 0);
    bool needsc = (iter != 0) || (m == 0);   // iter0: h rows m>0 are zero
    const float* wmB = Wm_g + l*1024 + c31;
    const float* wsB = Ws_g + l*1024 + c31;
    #pragma unroll
    for (int n2 = 0; n2 < NPB; n2++){ a2[n2] = 0.f; scv[n2] = 0.f; }
    #pragma unroll
    for (int q = 0; q < 8; q++){
      float w0 = wmB[(4*q+0)*32], w1 = wmB[(4*q+1)*32];
      float w2 = wmB[(4*q+2)*32], w3 = wmB[(4*q+3)*32];
      float t0 = 0.f, t1 = 0.f, t2 = 0.f, t3 = 0.f;
      if (needsc){
        t0 = wsB[(4*q+0)*32]; t1 = wsB[(4*q+1)*32];
        t2 = wsB[(4*q+2)*32]; t3 = wsB[(4*q+3)*32];
      }
      #pragma unroll
      for (int n2 = 0; n2 < NPB; n2++){
        float4 av = *(const float4*)(&abuf[n2][m*32 + 4*q]);
        a2[n2] = fmaf(av.x, w0, a2[n2]); a2[n2] = fmaf(av.y, w1, a2[n2]);
        a2[n2] = fmaf(av.z, w2, a2[n2]); a2[n2] = fmaf(av.w, w3, a2[n2]);
        if (needsc){
          float4 hv = (iter == 0)
            ? *(const float4*)(h0c + (size_t)(ng0+n2)*32 + 4*q)
            : *(const float4*)(hg_in + (size_t)(ng0+n2)*288 + m*32 + 4*q);
          scv[n2] = fmaf(hv.x, t0, scv[n2]); scv[n2] = fmaf(hv.y, t1, scv[n2]);
          scv[n2] = fmaf(hv.z, t2, scv[n2]); scv[n2] = fmaf(hv.w, t3, scv[n2]);
        }
      }
    }
  }
  __syncthreads();                              // all A reads done
  if (actm){
    #pragma unroll
    for (int n2 = 0; n2 < NPB; n2++){
      abuf[n2][idx0] = a2[n2];
      sbuf[n2][idx0] = scv[n2];
    }
  }
  __syncthreads();

  // ---- gate + h write + readout (wave w = node n)
  int spec = species[n];
  float sval = abuf[w][c31];
  float p1 = Wp1[spec*C+c31], p2 = Wp2[spec*C+c31], p3 = Wp3[spec*C+c31];
  float f = p1 + p2*sval + p3*sval*sval;
  #pragma unroll
  for (int it = 0; it < 5; it++){
    int idx = it*64 + lane;
    if (idx < 288){
      float hn = abuf[w][idx]*f + sbuf[w][idx];
      if (iter == 0) hg_out[(size_t)n*288 + idx] = hn;   // iter1: h dies here
      abuf[w][idx] = hn;
    }
  }

  int g = batch[n];
  float dv0 = 0.f, dv1 = 0.f, dv2 = 0.f, ev = 0.f;
  if (lane < 32){
    dv0 = abuf[w][32+lane]*wDv[lane];
    dv1 = abuf[w][64+lane]*wDv[lane];
    dv2 = abuf[w][96+lane]*wDv[lane];
  }
  if (iter == 0){
    if (lane < 32) ev = abuf[w][lane]*wEv[lane];
  } else {
    if (lane < 16){
      float hid = 0.f;
      #pragma unroll
      for (int c = 0; c < 32; c++) hid = fmaf(abuf[w][c], Whg[c*16+lane], hid);
      hid = silu_f(hid);
      ev = hid * wE2g[lane];
    }
  }
  #pragma unroll
  for (int off = 16; off >= 1; off >>= 1){
    ev  += __shfl_down(ev,  off);
    dv0 += __shfl_down(dv0, off);
    dv1 += __shfl_down(dv1, off);
    dv2 += __shfl_down(dv2, off);
  }
  if (lane == 0){
    if (iter == 0){
      ev += ae[spec];
      float q = charges[n];
      dv0 += q*pos[n*3+0];
      dv1 += q*pos[n*3+1];
      dv2 += q*pos[n*3+2];
    }
    atomicAdd(&glds[g][0], ev);
    atomicAdd(&glds[g][1], dv0);
    atomicAdd(&glds[g][2], dv1);
    atomicAdd(&glds[g][3], dv2);
  }
  __syncthreads();
  if (tid < NG*4){
    float v = glds[tid>>2][tid&3];
    if (v != 0.f) atomicAdd(out + tid, v);
  }
}

// ================================================================ launch
extern "C" void kernel_launch(void* const* d_in, const int* in_sizes, int n_in,
                              void* d_out, int out_size, void* d_ws, size_t ws_size,
                              hipStream_t stream){
  const float* positions       = (const float*)d_in[0];
  const float* node_attrs      = (const float*)d_in[1];
  const float* charges         = (const float*)d_in[2];
  const float* atomic_energies = (const float*)d_in[3];
  const float* W_embed         = (const float*)d_in[4];
  const float* R0              = (const float*)d_in[5];
  const float* R1              = (const float*)d_in[6];
  const float* R2              = (const float*)d_in[7];
  const float* R3              = (const float*)d_in[8];
  const float* W_mix           = (const float*)d_in[9];
  const float* W_sc            = (const float*)d_in[10];
  const float* Wp1             = (const float*)d_in[11];
  const float* Wp2             = (const float*)d_in[12];
  const float* Wp3             = (const float*)d_in[13];
  const float* wE1             = (const float*)d_in[14];
  const float* wD1             = (const float*)d_in[15];
  const float* Wh              = (const float*)d_in[16];
  const float* wE2             = (const float*)d_in[17];
  const float* wD2             = (const float*)d_in[18];
  const int*   edge_index      = (const int*)d_in[19];
  const int*   batch           = (const int*)d_in[20];
  float* out = (float*)d_out;

  char* wsp = (char*)d_ws;
  int*    bucket = (int*)wsp;    wsp += sizeof(int)*(size_t)N_NODES*CAP;
  float2* Tab2   = (float2*)wsp; wsp += sizeof(float2)*(size_t)2*TABN*96;
  float*  h0c    = (float*)wsp;  wsp += sizeof(float)*(size_t)N_NODES*32;
  float*  hg_mid = (float*)wsp;  wsp += sizeof(float)*(size_t)N_NODES*288;
  int* cursor    = (int*)wsp;    wsp += sizeof(int)*N_NODES;
  int* species   = (int*)wsp;    wsp += sizeof(int)*N_NODES;

  hipMemsetAsync(cursor, 0, N_NODES*sizeof(int), stream);

  prep_kernel<<<TB_H0, 256, 0, stream>>>(positions, edge_index, cursor, bucket,
                                         node_attrs, W_embed, species, h0c,
                                         R0, R1, R2, R3, Tab2, out);

  for (int i = 0; i < 2; i++){
    node_kernel<<<N_NODES/NPB, 512, 0, stream>>>(Tab2 + (size_t)i*TABN*96, bucket,
                                               cursor, h0c,
                                               hg_mid, hg_mid,
                                               W_mix + i*3*C*C, W_sc + i*3*C*C,
                                               Wp1 + i*Zn*C, Wp2 + i*Zn*C, Wp3 + i*Zn*C,
                                               species, batch,
                                               atomic_energies, charges, positions,
                                               wE1, (i == 0) ? wD1 : wD2,
                                               Wh, wE2, i, out);
  }
}

// Round 14
// 240.318 us; speedup vs baseline: 1.3433x; 1.3433x over previous
//
#include <hip/hip_runtime.h>
#include <math.h>

#define N_NODES 8192
#define N_EDGES 131072
#define C 32
#define Zn 10
#define NG 16
#define NB 8
#define H 64
#define TABN 4096
#define TPP 16     // table points per block (16 threads per point)
#define NPB 8      // nodes per node_kernel block (1 wave per node)
#define CAP 64     // bucket capacity per node
#define SL 48      // max edges processed per node

// prep block map
#define TB_TAB  514   // 2 * 257 table blocks (first: longest job)
#define TB_EDGE (TB_TAB + 512)
#define TB_H0   (TB_EDGE + 128)

__device__ __forceinline__ float silu_f(float v){ return v / (1.0f + __expf(-v)); }

// ================================================================ prep (fused):
// [0,514): radial MLP tables, 16 pts/block x 16 thr/pt
// [514,1026): edge filter + bucket snd write
// [1026,1154): species + compact h0c (1 MB) + d_out zero
__global__ __launch_bounds__(256)
void prep_kernel(const float* __restrict__ pos, const int* __restrict__ ei,
                 int* __restrict__ cursor, int* __restrict__ bucket,
                 const float* __restrict__ na, const float* __restrict__ Wemb,
                 int* __restrict__ species, float* __restrict__ h0c,
                 const float* __restrict__ R0g, const float* __restrict__ R1g,
                 const float* __restrict__ R2g, const float* __restrict__ R3g,
                 float2* __restrict__ Tab2, float* __restrict__ out){
  __shared__ float xsh[TPP*65];
  __shared__ int spec_lds[64];
  int b = blockIdx.x;
  int tid = threadIdx.x;

  if (b >= TB_TAB){
    if (b < TB_EDGE){
      // ---- edge filter + bucket
      int e = (b-TB_TAB)*256 + tid;
      int snd = ei[e], rcv = ei[N_EDGES + e];
      float px = pos[rcv*3+0]-pos[snd*3+0];
      float py = pos[rcv*3+1]-pos[snd*3+1];
      float pz = pos[rcv*3+2]-pos[snd*3+2];
      float r2 = px*px+py*py+pz*pz;
      if (r2 < 25.0f){
        int slot = atomicAdd(cursor + rcv, 1);
        if (slot < CAP) bucket[rcv*CAP + slot] = snd;
      }
    } else {
      // ---- species + compact h0
      int n0 = (b-TB_EDGE)*64;
      if (tid < 64){
        int n = n0 + tid;
        int spec = 0;
        #pragma unroll
        for (int z = 1; z < Zn; z++) if (na[n*Zn+z] > 0.5f) spec = z;
        species[n] = spec;
        spec_lds[tid] = spec;
      }
      if (b == TB_EDGE && tid >= 64 && tid < 128) out[tid-64] = 0.f;
      __syncthreads();
      float4* dst = (float4*)(h0c + (size_t)n0*32);
      #pragma unroll
      for (int it = 0; it < 2; it++){
        int f = it*256 + tid;          // [0, 512) float4s = 64 nodes x 8
        int node = f >> 3, q = f & 7;
        dst[f] = ((const float4*)(Wemb + spec_lds[node]*C))[q];
      }
    }
    return;
  }

  // ---- table part: 16 threads per point
  const int nb = 257;                // blocks per half
  int half = (b >= nb) ? 1 : 0;
  int blk  = b - half*nb;
  const float* R0i = R0g + half*NB*H;
  const float* R1i = R1g + half*H*H;
  const float* R2i = R2g + half*H*H;
  const float* R3i = R3g + half*H*96;
  float2* TabH = Tab2 + (size_t)half*((size_t)TABN*96);

  int pl = tid >> 4, jt = tid & 15;
  int i = blk*TPP + pl;
  float r = (i == 0) ? 1e-6f : (float)i * (5.0f/TABN);
  if (jt < 8){
    float xr = r*0.2f;
    float env = 0.f;
    if (xr < 1.0f){
      float x2 = xr*xr, x5 = x2*x2*xr;
      env = 1.f - 21.f*x5 + 35.f*x5*xr - 15.f*x5*x2;
    }
    float sc = 0.6324555320336759f / r * env;
    xsh[pl*65 + jt] = sc * sinf((float)(jt+1)*0.6283185307179586f*r);
  }
  __syncthreads();

  float acc[6];
  // L0: 8 -> 64, 4 cols/thread
  #pragma unroll
  for (int j = 0; j < 4; j++) acc[j] = 0.f;
  #pragma unroll
  for (int k = 0; k < 8; k++){
    float xk = xsh[pl*65 + k];
    float4 w = *(const float4*)(R0i + k*H + jt*4);
    acc[0]=fmaf(xk,w.x,acc[0]); acc[1]=fmaf(xk,w.y,acc[1]);
    acc[2]=fmaf(xk,w.z,acc[2]); acc[3]=fmaf(xk,w.w,acc[3]);
  }
  __syncthreads();
  #pragma unroll
  for (int j = 0; j < 4; j++) xsh[pl*65 + jt*4 + j] = silu_f(acc[j]);
  __syncthreads();

  const float* Wl[2] = {R1i, R2i};
  #pragma unroll
  for (int L = 0; L < 2; L++){
    const float* W = Wl[L];
    #pragma unroll
    for (int j = 0; j < 4; j++) acc[j] = 0.f;
    #pragma unroll 8
    for (int k = 0; k < H; k++){
      float xk = xsh[pl*65 + k];
      float4 w = *(const float4*)(W + k*H + jt*4);
      acc[0]=fmaf(xk,w.x,acc[0]); acc[1]=fmaf(xk,w.y,acc[1]);
      acc[2]=fmaf(xk,w.z,acc[2]); acc[3]=fmaf(xk,w.w,acc[3]);
    }
    __syncthreads();
    #pragma unroll
    for (int j = 0; j < 4; j++) xsh[pl*65 + jt*4 + j] = silu_f(acc[j]);
    __syncthreads();
  }

  // L3: 64 -> 96, 6 cols/thread
  #pragma unroll
  for (int j = 0; j < 6; j++) acc[j] = 0.f;
  #pragma unroll 8
  for (int k = 0; k < H; k++){
    float xk = xsh[pl*65 + k];
    const float* wp = R3i + k*96 + jt*6;
    float2 w0 = *(const float2*)(wp);
    float2 w1 = *(const float2*)(wp+2);
    float2 w2 = *(const float2*)(wp+4);
    acc[0]=fmaf(xk,w0.x,acc[0]); acc[1]=fmaf(xk,w0.y,acc[1]);
    acc[2]=fmaf(xk,w1.x,acc[2]); acc[3]=fmaf(xk,w1.y,acc[3]);
    acc[4]=fmaf(xk,w2.x,acc[4]); acc[5]=fmaf(xk,w2.y,acc[5]);
  }
  if (i <= TABN){
    int cb = jt*6;
    #pragma unroll
    for (int j = 0; j < 6; j++){
      int c = cb + j;
      float val = acc[j];
      if (i < TABN) TabH[(size_t)i*96 + c].x = val;      // lerp lower endpoint
      if (i > 0)    TabH[(size_t)(i-1)*96 + c].y = val;  // lerp upper endpoint
    }
  }
}

// ================================================================ node (ITER compile-time):
// lane-parallel preamble -> dependency-free gather -> global-weight mix
// -> gate -> readout.  ITER=0: h from compact h0c (1 MB, L2-hot), writes hg.
// ITER=1: h from hg, no dead h write.  Single load path per instantiation.
template<int ITER>
__global__ __launch_bounds__(512)
void node_kernel(const float2* __restrict__ Tab2, const int* __restrict__ bucket,
                 const int* __restrict__ deg, const float* __restrict__ h0c,
                 const float* __restrict__ hg_in, float* __restrict__ hg_out,
                 const float* __restrict__ Wm_g, const float* __restrict__ Ws_g,
                 const float* __restrict__ Wp1, const float* __restrict__ Wp2,
                 const float* __restrict__ Wp3,
                 const int* __restrict__ species, const int* __restrict__ batch,
                 const float* __restrict__ ae, const float* __restrict__ charges,
                 const float* __restrict__ pos,
                 const float* __restrict__ wEv, const float* __restrict__ wDv,
                 const float* __restrict__ Whg, const float* __restrict__ wE2g,
                 float* __restrict__ out){
  __shared__ float abuf[NPB][288];    // A (gather) -> A-mixed -> h_new
  __shared__ float sbuf[NPB][288];    // estage during gather -> sc after mix
  __shared__ float glds[NG][4];
  float* estage = &sbuf[0][0];        // NPB*SL*6 = 2304 = NPB*288, exact alias
  int tid = threadIdx.x;
  if (tid < NG*4) glds[tid>>2][tid&3] = 0.f;
  int w = tid >> 6, lane = tid & 63;
  int c31 = lane & 31;
  bool hi = lane >= 32;
  int ng0 = blockIdx.x*NPB;
  int n = ng0 + w;

  // ---- lane-parallel preamble: stage all edge params
  int cnt = deg[n]; if (cnt > SL) cnt = SL;
  if (lane < cnt){
    int snd = bucket[n*CAP + lane];
    float px = pos[n*3+0] - pos[snd*3+0];
    float py = pos[n*3+1] - pos[snd*3+1];
    float pz = pos[n*3+2] - pos[snd*3+2];
    float r = sqrtf(px*px+py*py+pz*pz + 1e-12f);
    float inv = 1.0f/r;
    float* es = estage + (w*SL + lane)*6;
    es[0] = px*inv; es[1] = py*inv; es[2] = pz*inv;
    es[3] = r * (TABN/5.0f);
    es[4] = __int_as_float(snd);
  }

  // ---- gather: only independent loads per edge (3 table + 1 hs)
  const float s3 = 1.7320508075688772f;
  const float s5 = 2.23606797749979f;
  const float s15 = 3.872983346207417f;
  int colA = (hi ? 32 : 0) + c31;
  int colB = 32 + c31;
  int colC = 64 + c31;
  float acc0=0.f, acc1=0.f, acc2=0.f, acc3=0.f, acc4=0.f;
  #pragma unroll 4
  for (int j = 0; j < cnt; j++){
    const float* es = estage + (w*SL + j)*6;
    float x = es[0], y = es[1], z = es[2], u = es[3];
    int snd = __float_as_int(es[4]);
    int i0 = (int)u;
    if (i0 > TABN-1) i0 = TABN-1;
    float f = u - (float)i0;
    const float2* T2 = Tab2 + (size_t)i0*96;
    float hs;
    if (ITER == 0) hs = h0c[(size_t)snd*32 + c31];
    else           hs = hg_in[(size_t)snd*288 + c31];
    float2 ta = T2[colA];
    float2 tb = T2[colB];
    float2 tc = T2[colC];
    float wv0 = fmaf(ta.y - ta.x, f, ta.x) * hs;
    float wv1 = fmaf(tb.y - tb.x, f, tb.x) * hs;
    float wv2 = fmaf(tc.y - tc.x, f, tc.x) * hs;
    float Ys0 = hi ? s3*x : 1.0f;
    float Ys1 = s3 * (hi ? z : y);
    float Ys2 = s15 * (hi ? y*z : x*y);
    float Ys3 = hi ? s15*x*z : 0.5f*s5*(3.f*z*z - 1.f);
    float Ys4 = 0.5f*s15*(x*x - y*y);
    acc0 = fmaf(wv0, Ys0, acc0);
    acc1 = fmaf(wv1, Ys1, acc1);
    acc2 = fmaf(wv2, Ys2, acc2);
    acc3 = fmaf(wv2, Ys3, acc3);
    acc4 = fmaf(wv2, Ys4, acc4);
  }
  __syncthreads();                    // estage fully consumed (aliases sbuf)
  abuf[w][lane]       = acc0 * (1.0f/16.0f);
  abuf[w][lane + 64]  = acc1 * (1.0f/16.0f);
  abuf[w][lane + 128] = acc2 * (1.0f/16.0f);
  abuf[w][lane + 192] = acc3 * (1.0f/16.0f);
  if (!hi) abuf[w][lane + 256] = acc4 * (1.0f/16.0f);
  __syncthreads();

  // ---- mix: waves 0..4 each own slot w across the 8 nodes
  float a2[NPB], scv[NPB];
  int idx0 = w*64 + lane;
  bool actm = (w < 5) && (idx0 < 288);
  if (w < 5){
    int m = idx0 >> 5; if (m > 8) m = 8;
    int l = (m >= 4) ? 2 : ((m >= 1) ? 1 : 0);
    bool needsc = (ITER != 0) || (m == 0);   // iter0: h rows m>0 are zero
    const float* wmB = Wm_g + l*1024 + c31;
    const float* wsB = Ws_g + l*1024 + c31;
    #pragma unroll
    for (int n2 = 0; n2 < NPB; n2++){ a2[n2] = 0.f; scv[n2] = 0.f; }
    #pragma unroll
    for (int q = 0; q < 8; q++){
      float w0 = wmB[(4*q+0)*32], w1 = wmB[(4*q+1)*32];
      float w2 = wmB[(4*q+2)*32], w3 = wmB[(4*q+3)*32];
      float t0 = 0.f, t1 = 0.f, t2 = 0.f, t3 = 0.f;
      if (needsc){
        t0 = wsB[(4*q+0)*32]; t1 = wsB[(4*q+1)*32];
        t2 = wsB[(4*q+2)*32]; t3 = wsB[(4*q+3)*32];
      }
      #pragma unroll
      for (int n2 = 0; n2 < NPB; n2++){
        float4 av = *(const float4*)(&abuf[n2][m*32 + 4*q]);
        a2[n2] = fmaf(av.x, w0, a2[n2]); a2[n2] = fmaf(av.y, w1, a2[n2]);
        a2[n2] = fmaf(av.z, w2, a2[n2]); a2[n2] = fmaf(av.w, w3, a2[n2]);
        if (needsc){
          float4 hv;
          if (ITER == 0) hv = *(const float4*)(h0c + (size_t)(ng0+n2)*32 + 4*q);
          else           hv = *(const float4*)(hg_in + (size_t)(ng0+n2)*288 + m*32 + 4*q);
          scv[n2] = fmaf(hv.x, t0, scv[n2]); scv[n2] = fmaf(hv.y, t1, scv[n2]);
          scv[n2] = fmaf(hv.z, t2, scv[n2]); scv[n2] = fmaf(hv.w, t3, scv[n2]);
        }
      }
    }
  }
  __syncthreads();                              // all A reads done
  if (actm){
    #pragma unroll
    for (int n2 = 0; n2 < NPB; n2++){
      abuf[n2][idx0] = a2[n2];
      sbuf[n2][idx0] = scv[n2];
    }
  }
  __syncthreads();

  // ---- gate + h write + readout (wave w = node n)
  int spec = species[n];
  float sval = abuf[w][c31];
  float p1 = Wp1[spec*C+c31], p2 = Wp2[spec*C+c31], p3 = Wp3[spec*C+c31];
  float f = p1 + p2*sval + p3*sval*sval;
  #pragma unroll
  for (int it = 0; it < 5; it++){
    int idx = it*64 + lane;
    if (idx < 288){
      float hn = abuf[w][idx]*f + sbuf[w][idx];
      if (ITER == 0) hg_out[(size_t)n*288 + idx] = hn;   // iter1: h dies here
      abuf[w][idx] = hn;
    }
  }

  int g = batch[n];
  float dv0 = 0.f, dv1 = 0.f, dv2 = 0.f, ev = 0.f;
  if (lane < 32){
    dv0 = abuf[w][32+lane]*wDv[lane];
    dv1 = abuf[w][64+lane]*wDv[lane];
    dv2 = abuf[w][96+lane]*wDv[lane];
  }
  if (ITER == 0){
    if (lane < 32) ev = abuf[w][lane]*wEv[lane];
  } else {
    if (lane < 16){
      float hid = 0.f;
      #pragma unroll
      for (int c = 0; c < 32; c++) hid = fmaf(abuf[w][c], Whg[c*16+lane], hid);
      hid = silu_f(hid);
      ev = hid * wE2g[lane];
    }
  }
  #pragma unroll
  for (int off = 16; off >= 1; off >>= 1){
    ev  += __shfl_down(ev,  off);
    dv0 += __shfl_down(dv0, off);
    dv1 += __shfl_down(dv1, off);
    dv2 += __shfl_down(dv2, off);
  }
  if (lane == 0){
    if (ITER == 0){
      ev += ae[spec];
      float q = charges[n];
      dv0 += q*pos[n*3+0];
      dv1 += q*pos[n*3+1];
      dv2 += q*pos[n*3+2];
    }
    atomicAdd(&glds[g][0], ev);
    atomicAdd(&glds[g][1], dv0);
    atomicAdd(&glds[g][2], dv1);
    atomicAdd(&glds[g][3], dv2);
  }
  __syncthreads();
  if (tid < NG*4){
    float v = glds[tid>>2][tid&3];
    if (v != 0.f) atomicAdd(out + tid, v);
  }
}

// ================================================================ launch
extern "C" void kernel_launch(void* const* d_in, const int* in_sizes, int n_in,
                              void* d_out, int out_size, void* d_ws, size_t ws_size,
                              hipStream_t stream){
  const float* positions       = (const float*)d_in[0];
  const float* node_attrs      = (const float*)d_in[1];
  const float* charges         = (const float*)d_in[2];
  const float* atomic_energies = (const float*)d_in[3];
  const float* W_embed         = (const float*)d_in[4];
  const float* R0              = (const float*)d_in[5];
  const float* R1              = (const float*)d_in[6];
  const float* R2              = (const float*)d_in[7];
  const float* R3              = (const float*)d_in[8];
  const float* W_mix           = (const float*)d_in[9];
  const float* W_sc            = (const float*)d_in[10];
  const float* Wp1             = (const float*)d_in[11];
  const float* Wp2             = (const float*)d_in[12];
  const float* Wp3             = (const float*)d_in[13];
  const float* wE1             = (const float*)d_in[14];
  const float* wD1             = (const float*)d_in[15];
  const float* Wh              = (const float*)d_in[16];
  const float* wE2             = (const float*)d_in[17];
  const float* wD2             = (const float*)d_in[18];
  const int*   edge_index      = (const int*)d_in[19];
  const int*   batch           = (const int*)d_in[20];
  float* out = (float*)d_out;

  char* wsp = (char*)d_ws;
  int*    bucket = (int*)wsp;    wsp += sizeof(int)*(size_t)N_NODES*CAP;
  float2* Tab2   = (float2*)wsp; wsp += sizeof(float2)*(size_t)2*TABN*96;
  float*  h0c    = (float*)wsp;  wsp += sizeof(float)*(size_t)N_NODES*32;
  float*  hg_mid = (float*)wsp;  wsp += sizeof(float)*(size_t)N_NODES*288;
  int* cursor    = (int*)wsp;    wsp += sizeof(int)*N_NODES;
  int* species   = (int*)wsp;    wsp += sizeof(int)*N_NODES;

  hipMemsetAsync(cursor, 0, N_NODES*sizeof(int), stream);

  prep_kernel<<<TB_H0, 256, 0, stream>>>(positions, edge_index, cursor, bucket,
                                         node_attrs, W_embed, species, h0c,
                                         R0, R1, R2, R3, Tab2, out);

  node_kernel<0><<<N_NODES/NPB, 512, 0, stream>>>(Tab2, bucket,
                                               cursor, h0c, hg_mid, hg_mid,
                                               W_mix, W_sc,
                                               Wp1, Wp2, Wp3,
                                               species, batch,
                                               atomic_energies, charges, positions,
                                               wE1, wD1, Wh, wE2, out);
  node_kernel<1><<<N_NODES/NPB, 512, 0, stream>>>(Tab2 + (size_t)TABN*96, bucket,
                                               cursor, h0c, hg_mid, hg_mid,
                                               W_mix + 3*C*C, W_sc + 3*C*C,
                                               Wp1 + Zn*C, Wp2 + Zn*C, Wp3 + Zn*C,
                                               species, batch,
                                               atomic_energies, charges, positions,
                                               wE1, wD2, Wh, wE2, out);
}

// Round 15
// 239.425 us; speedup vs baseline: 1.3483x; 1.0037x over previous
//
#include <hip/hip_runtime.h>
#include <math.h>

#define N_NODES 8192
#define N_EDGES 131072
#define C 32
#define Zn 10
#define NG 16
#define NB 8
#define H 64
#define TABN 4096
#define TPP 16     // table points per block (16 threads per point)
#define NPB 8      // nodes per node_kernel block (1 wave per node)
#define CAP 64     // bucket capacity per node
#define SL 48      // max edges processed per node

// prep block map
#define TB_TAB  514   // 2 * 257 table blocks (first: longest job)
#define TB_EDGE (TB_TAB + 512)
#define TB_H0   (TB_EDGE + 128)

__device__ __forceinline__ float silu_f(float v){ return v / (1.0f + __expf(-v)); }

// ================================================================ prep (fused):
// [0,514): radial MLP tables, 16 pts/block x 16 thr/pt
// [514,1026): edge filter + bucket snd write
// [1026,1154): species + compact h0c (1 MB) + d_out zero
__global__ __launch_bounds__(256)
void prep_kernel(const float* __restrict__ pos, const int* __restrict__ ei,
                 int* __restrict__ cursor, int* __restrict__ bucket,
                 const float* __restrict__ na, const float* __restrict__ Wemb,
                 int* __restrict__ species, float* __restrict__ h0c,
                 const float* __restrict__ R0g, const float* __restrict__ R1g,
                 const float* __restrict__ R2g, const float* __restrict__ R3g,
                 float2* __restrict__ Tab2, float* __restrict__ out){
  __shared__ float xsh[TPP*65];
  __shared__ int spec_lds[64];
  int b = blockIdx.x;
  int tid = threadIdx.x;

  if (b >= TB_TAB){
    if (b < TB_EDGE){
      // ---- edge filter + bucket
      int e = (b-TB_TAB)*256 + tid;
      int snd = ei[e], rcv = ei[N_EDGES + e];
      float px = pos[rcv*3+0]-pos[snd*3+0];
      float py = pos[rcv*3+1]-pos[snd*3+1];
      float pz = pos[rcv*3+2]-pos[snd*3+2];
      float r2 = px*px+py*py+pz*pz;
      if (r2 < 25.0f){
        int slot = atomicAdd(cursor + rcv, 1);
        if (slot < CAP) bucket[rcv*CAP + slot] = snd;
      }
    } else {
      // ---- species + compact h0
      int n0 = (b-TB_EDGE)*64;
      if (tid < 64){
        int n = n0 + tid;
        int spec = 0;
        #pragma unroll
        for (int z = 1; z < Zn; z++) if (na[n*Zn+z] > 0.5f) spec = z;
        species[n] = spec;
        spec_lds[tid] = spec;
      }
      if (b == TB_EDGE && tid >= 64 && tid < 128) out[tid-64] = 0.f;
      __syncthreads();
      float4* dst = (float4*)(h0c + (size_t)n0*32);
      #pragma unroll
      for (int it = 0; it < 2; it++){
        int f = it*256 + tid;          // [0, 512) float4s = 64 nodes x 8
        int node = f >> 3, q = f & 7;
        dst[f] = ((const float4*)(Wemb + spec_lds[node]*C))[q];
      }
    }
    return;
  }

  // ---- table part: 16 threads per point
  const int nb = 257;                // blocks per half
  int half = (b >= nb) ? 1 : 0;
  int blk  = b - half*nb;
  const float* R0i = R0g + half*NB*H;
  const float* R1i = R1g + half*H*H;
  const float* R2i = R2g + half*H*H;
  const float* R3i = R3g + half*H*96;
  float2* TabH = Tab2 + (size_t)half*((size_t)TABN*96);

  int pl = tid >> 4, jt = tid & 15;
  int i = blk*TPP + pl;
  float r = (i == 0) ? 1e-6f : (float)i * (5.0f/TABN);
  if (jt < 8){
    float xr = r*0.2f;
    float env = 0.f;
    if (xr < 1.0f){
      float x2 = xr*xr, x5 = x2*x2*xr;
      env = 1.f - 21.f*x5 + 35.f*x5*xr - 15.f*x5*x2;
    }
    float sc = 0.6324555320336759f / r * env;
    xsh[pl*65 + jt] = sc * sinf((float)(jt+1)*0.6283185307179586f*r);
  }
  __syncthreads();

  float acc[6];
  // L0: 8 -> 64, 4 cols/thread
  #pragma unroll
  for (int j = 0; j < 4; j++) acc[j] = 0.f;
  #pragma unroll
  for (int k = 0; k < 8; k++){
    float xk = xsh[pl*65 + k];
    float4 w = *(const float4*)(R0i + k*H + jt*4);
    acc[0]=fmaf(xk,w.x,acc[0]); acc[1]=fmaf(xk,w.y,acc[1]);
    acc[2]=fmaf(xk,w.z,acc[2]); acc[3]=fmaf(xk,w.w,acc[3]);
  }
  __syncthreads();
  #pragma unroll
  for (int j = 0; j < 4; j++) xsh[pl*65 + jt*4 + j] = silu_f(acc[j]);
  __syncthreads();

  const float* Wl[2] = {R1i, R2i};
  #pragma unroll
  for (int L = 0; L < 2; L++){
    const float* W = Wl[L];
    #pragma unroll
    for (int j = 0; j < 4; j++) acc[j] = 0.f;
    #pragma unroll 8
    for (int k = 0; k < H; k++){
      float xk = xsh[pl*65 + k];
      float4 w = *(const float4*)(W + k*H + jt*4);
      acc[0]=fmaf(xk,w.x,acc[0]); acc[1]=fmaf(xk,w.y,acc[1]);
      acc[2]=fmaf(xk,w.z,acc[2]); acc[3]=fmaf(xk,w.w,acc[3]);
    }
    __syncthreads();
    #pragma unroll
    for (int j = 0; j < 4; j++) xsh[pl*65 + jt*4 + j] = silu_f(acc[j]);
    __syncthreads();
  }

  // L3: 64 -> 96, 6 cols/thread
  #pragma unroll
  for (int j = 0; j < 6; j++) acc[j] = 0.f;
  #pragma unroll 8
  for (int k = 0; k < H; k++){
    float xk = xsh[pl*65 + k];
    const float* wp = R3i + k*96 + jt*6;
    float2 w0 = *(const float2*)(wp);
    float2 w1 = *(const float2*)(wp+2);
    float2 w2 = *(const float2*)(wp+4);
    acc[0]=fmaf(xk,w0.x,acc[0]); acc[1]=fmaf(xk,w0.y,acc[1]);
    acc[2]=fmaf(xk,w1.x,acc[2]); acc[3]=fmaf(xk,w1.y,acc[3]);
    acc[4]=fmaf(xk,w2.x,acc[4]); acc[5]=fmaf(xk,w2.y,acc[5]);
  }
  if (i <= TABN){
    int cb = jt*6;
    #pragma unroll
    for (int j = 0; j < 6; j++){
      int c = cb + j;
      float val = acc[j];
      if (i < TABN) TabH[(size_t)i*96 + c].x = val;      // lerp lower endpoint
      if (i > 0)    TabH[(size_t)(i-1)*96 + c].y = val;  // lerp upper endpoint
    }
  }
}

// ================================================================ node (ITER compile-time):
// LDS-transposed mix weights (short-latency ds_read -> no VGPR hoist/spill),
// lane-parallel preamble, dependency-free gather, gate, readout.
// ITER=0: h from compact h0c (L2-hot), writes hg.  ITER=1: h from hg, no dead write.
template<int ITER>
__global__ __launch_bounds__(512)
void node_kernel(const float2* __restrict__ Tab2, const int* __restrict__ bucket,
                 const int* __restrict__ deg, const float* __restrict__ h0c,
                 const float* __restrict__ hg_in, float* __restrict__ hg_out,
                 const float* __restrict__ Wm_g, const float* __restrict__ Ws_g,
                 const float* __restrict__ Wp1, const float* __restrict__ Wp2,
                 const float* __restrict__ Wp3,
                 const int* __restrict__ species, const int* __restrict__ batch,
                 const float* __restrict__ ae, const float* __restrict__ charges,
                 const float* __restrict__ pos,
                 const float* __restrict__ wEv, const float* __restrict__ wDv,
                 const float* __restrict__ Whg, const float* __restrict__ wE2g,
                 float* __restrict__ out){
  __shared__ float WmT[3*32*34];      // [l][d][c], stride 34 (2-way banks, b64-aligned)
  __shared__ float WsT[3*32*34];
  __shared__ float abuf[NPB][288];    // A (gather) -> A-mixed -> h_new
  __shared__ float sbuf[NPB][288];    // estage during gather -> sc after mix
  __shared__ float glds[NG][4];
  float* estage = &sbuf[0][0];        // NPB*SL*6 = 2304 = NPB*288, exact alias
  int tid = threadIdx.x;
  for (int t = tid; t < 3072; t += 512){
    int l = t >> 10, rem = t & 1023, c = rem >> 5, d = rem & 31;
    WmT[(l*32+d)*34 + c] = Wm_g[t];
    WsT[(l*32+d)*34 + c] = Ws_g[t];
  }
  if (tid < NG*4) glds[tid>>2][tid&3] = 0.f;
  int w = tid >> 6, lane = tid & 63;
  int c31 = lane & 31;
  bool hi = lane >= 32;
  int ng0 = blockIdx.x*NPB;
  int n = ng0 + w;

  // ---- lane-parallel preamble: stage all edge params
  int cnt = deg[n]; if (cnt > SL) cnt = SL;
  if (lane < cnt){
    int snd = bucket[n*CAP + lane];
    float px = pos[n*3+0] - pos[snd*3+0];
    float py = pos[n*3+1] - pos[snd*3+1];
    float pz = pos[n*3+2] - pos[snd*3+2];
    float r = sqrtf(px*px+py*py+pz*pz + 1e-12f);
    float inv = 1.0f/r;
    float* es = estage + (w*SL + lane)*6;
    es[0] = px*inv; es[1] = py*inv; es[2] = pz*inv;
    es[3] = r * (TABN/5.0f);
    es[4] = __int_as_float(snd);
  }

  // ---- gather: only independent loads per edge (3 table + 1 hs)
  const float s3 = 1.7320508075688772f;
  const float s5 = 2.23606797749979f;
  const float s15 = 3.872983346207417f;
  int colA = (hi ? 32 : 0) + c31;
  int colB = 32 + c31;
  int colC = 64 + c31;
  float acc0=0.f, acc1=0.f, acc2=0.f, acc3=0.f, acc4=0.f;
  #pragma unroll 4
  for (int j = 0; j < cnt; j++){
    const float* es = estage + (w*SL + j)*6;
    float x = es[0], y = es[1], z = es[2], u = es[3];
    int snd = __float_as_int(es[4]);
    int i0 = (int)u;
    if (i0 > TABN-1) i0 = TABN-1;
    float f = u - (float)i0;
    const float2* T2 = Tab2 + (size_t)i0*96;
    float hs;
    if (ITER == 0) hs = h0c[(size_t)snd*32 + c31];
    else           hs = hg_in[(size_t)snd*288 + c31];
    float2 ta = T2[colA];
    float2 tb = T2[colB];
    float2 tc = T2[colC];
    float wv0 = fmaf(ta.y - ta.x, f, ta.x) * hs;
    float wv1 = fmaf(tb.y - tb.x, f, tb.x) * hs;
    float wv2 = fmaf(tc.y - tc.x, f, tc.x) * hs;
    float Ys0 = hi ? s3*x : 1.0f;
    float Ys1 = s3 * (hi ? z : y);
    float Ys2 = s15 * (hi ? y*z : x*y);
    float Ys3 = hi ? s15*x*z : 0.5f*s5*(3.f*z*z - 1.f);
    float Ys4 = 0.5f*s15*(x*x - y*y);
    acc0 = fmaf(wv0, Ys0, acc0);
    acc1 = fmaf(wv1, Ys1, acc1);
    acc2 = fmaf(wv2, Ys2, acc2);
    acc3 = fmaf(wv2, Ys3, acc3);
    acc4 = fmaf(wv2, Ys4, acc4);
  }
  __syncthreads();                    // estage fully consumed (aliases sbuf)
  abuf[w][lane]       = acc0 * (1.0f/16.0f);
  abuf[w][lane + 64]  = acc1 * (1.0f/16.0f);
  abuf[w][lane + 128] = acc2 * (1.0f/16.0f);
  abuf[w][lane + 192] = acc3 * (1.0f/16.0f);
  if (!hi) abuf[w][lane + 256] = acc4 * (1.0f/16.0f);
  __syncthreads();

  // ---- mix: waves 0..4 each own slot w across the 8 nodes; weights from LDS
  float a2[NPB], scv[NPB];
  int idx0 = w*64 + lane;
  bool actm = (w < 5) && (idx0 < 288);
  if (w < 5){
    int m = idx0 >> 5; if (m > 8) m = 8;
    int l = (m >= 4) ? 2 : ((m >= 1) ? 1 : 0);
    bool needsc = (ITER != 0) || (m == 0);   // iter0: h rows m>0 are zero
    const float* wmB = WmT + (l*32 + c31)*34;
    const float* wsB = WsT + (l*32 + c31)*34;
    #pragma unroll
    for (int n2 = 0; n2 < NPB; n2++){ a2[n2] = 0.f; scv[n2] = 0.f; }
    #pragma unroll
    for (int q = 0; q < 8; q++){
      float2 wa0 = *(const float2*)(wmB + 4*q);
      float2 wa1 = *(const float2*)(wmB + 4*q + 2);
      float2 sa0 = *(const float2*)(wsB + 4*q);
      float2 sa1 = *(const float2*)(wsB + 4*q + 2);
      #pragma unroll
      for (int n2 = 0; n2 < NPB; n2++){
        float4 av = *(const float4*)(&abuf[n2][m*32 + 4*q]);
        a2[n2] = fmaf(av.x, wa0.x, a2[n2]); a2[n2] = fmaf(av.y, wa0.y, a2[n2]);
        a2[n2] = fmaf(av.z, wa1.x, a2[n2]); a2[n2] = fmaf(av.w, wa1.y, a2[n2]);
        if (needsc){
          float4 hv;
          if (ITER == 0) hv = *(const float4*)(h0c + (size_t)(ng0+n2)*32 + 4*q);
          else           hv = *(const float4*)(hg_in + (size_t)(ng0+n2)*288 + m*32 + 4*q);
          scv[n2] = fmaf(hv.x, sa0.x, scv[n2]); scv[n2] = fmaf(hv.y, sa0.y, scv[n2]);
          scv[n2] = fmaf(hv.z, sa1.x, scv[n2]); scv[n2] = fmaf(hv.w, sa1.y, scv[n2]);
        }
      }
    }
  }
  __syncthreads();                              // all A reads done
  if (actm){
    #pragma unroll
    for (int n2 = 0; n2 < NPB; n2++){
      abuf[n2][idx0] = a2[n2];
      sbuf[n2][idx0] = scv[n2];
    }
  }
  __syncthreads();

  // ---- gate + h write + readout (wave w = node n)
  int spec = species[n];
  float sval = abuf[w][c31];
  float p1 = Wp1[spec*C+c31], p2 = Wp2[spec*C+c31], p3 = Wp3[spec*C+c31];
  float f = p1 + p2*sval + p3*sval*sval;
  #pragma unroll
  for (int it = 0; it < 5; it++){
    int idx = it*64 + lane;
    if (idx < 288){
      float hn = abuf[w][idx]*f + sbuf[w][idx];
      if (ITER == 0) hg_out[(size_t)n*288 + idx] = hn;   // iter1: h dies here
      abuf[w][idx] = hn;
    }
  }

  int g = batch[n];
  float dv0 = 0.f, dv1 = 0.f, dv2 = 0.f, ev = 0.f;
  if (lane < 32){
    dv0 = abuf[w][32+lane]*wDv[lane];
    dv1 = abuf[w][64+lane]*wDv[lane];
    dv2 = abuf[w][96+lane]*wDv[lane];
  }
  if (ITER == 0){
    if (lane < 32) ev = abuf[w][lane]*wEv[lane];
  } else {
    if (lane < 16){
      float hid = 0.f;
      #pragma unroll
      for (int c = 0; c < 32; c++) hid = fmaf(abuf[w][c], Whg[c*16+lane], hid);
      hid = silu_f(hid);
      ev = hid * wE2g[lane];
    }
  }
  #pragma unroll
  for (int off = 16; off >= 1; off >>= 1){
    ev  += __shfl_down(ev,  off);
    dv0 += __shfl_down(dv0, off);
    dv1 += __shfl_down(dv1, off);
    dv2 += __shfl_down(dv2, off);
  }
  if (lane == 0){
    if (ITER == 0){
      ev += ae[spec];
      float q = charges[n];
      dv0 += q*pos[n*3+0];
      dv1 += q*pos[n*3+1];
      dv2 += q*pos[n*3+2];
    }
    atomicAdd(&glds[g][0], ev);
    atomicAdd(&glds[g][1], dv0);
    atomicAdd(&glds[g][2], dv1);
    atomicAdd(&glds[g][3], dv2);
  }
  __syncthreads();
  if (tid < NG*4){
    float v = glds[tid>>2][tid&3];
    if (v != 0.f) atomicAdd(out + tid, v);
  }
}

// ================================================================ launch
extern "C" void kernel_launch(void* const* d_in, const int* in_sizes, int n_in,
                              void* d_out, int out_size, void* d_ws, size_t ws_size,
                              hipStream_t stream){
  const float* positions       = (const float*)d_in[0];
  const float* node_attrs      = (const float*)d_in[1];
  const float* charges         = (const float*)d_in[2];
  const float* atomic_energies = (const float*)d_in[3];
  const float* W_embed         = (const float*)d_in[4];
  const float* R0              = (const float*)d_in[5];
  const float* R1              = (const float*)d_in[6];
  const float* R2              = (const float*)d_in[7];
  const float* R3              = (const float*)d_in[8];
  const float* W_mix           = (const float*)d_in[9];
  const float* W_sc            = (const float*)d_in[10];
  const float* Wp1             = (const float*)d_in[11];
  const float* Wp2             = (const float*)d_in[12];
  const float* Wp3             = (const float*)d_in[13];
  const float* wE1             = (const float*)d_in[14];
  const float* wD1             = (const float*)d_in[15];
  const float* Wh              = (const float*)d_in[16];
  const float* wE2             = (const float*)d_in[17];
  const float* wD2             = (const float*)d_in[18];
  const int*   edge_index      = (const int*)d_in[19];
  const int*   batch           = (const int*)d_in[20];
  float* out = (float*)d_out;

  char* wsp = (char*)d_ws;
  int*    bucket = (int*)wsp;    wsp += sizeof(int)*(size_t)N_NODES*CAP;
  float2* Tab2   = (float2*)wsp; wsp += sizeof(float2)*(size_t)2*TABN*96;
  float*  h0c    = (float*)wsp;  wsp += sizeof(float)*(size_t)N_NODES*32;
  float*  hg_mid = (float*)wsp;  wsp += sizeof(float)*(size_t)N_NODES*288;
  int* cursor    = (int*)wsp;    wsp += sizeof(int)*N_NODES;
  int* species   = (int*)wsp;    wsp += sizeof(int)*N_NODES;

  hipMemsetAsync(cursor, 0, N_NODES*sizeof(int), stream);

  prep_kernel<<<TB_H0, 256, 0, stream>>>(positions, edge_index, cursor, bucket,
                                         node_attrs, W_embed, species, h0c,
                                         R0, R1, R2, R3, Tab2, out);

  node_kernel<0><<<N_NODES/NPB, 512, 0, stream>>>(Tab2, bucket,
                                               cursor, h0c, hg_mid, hg_mid,
                                               W_mix, W_sc,
                                               Wp1, Wp2, Wp3,
                                               species, batch,
                                               atomic_energies, charges, positions,
                                               wE1, wD1, Wh, wE2, out);
  node_kernel<1><<<N_NODES/NPB, 512, 0, stream>>>(Tab2 + (size_t)TABN*96, bucket,
                                               cursor, h0c, hg_mid, hg_mid,
                                               W_mix + 3*C*C, W_sc + 3*C*C,
                                               Wp1 + Zn*C, Wp2 + Zn*C, Wp3 + Zn*C,
                                               species, batch,
                                               atomic_energies, charges, positions,
                                               wE1, wD2, Wh, wE2, out);
}

// Round 16
// 201.920 us; speedup vs baseline: 1.5987x; 1.1857x over previous
//
#include <hip/hip_runtime.h>
#include <math.h>

#define N_NODES 8192
#define N_EDGES 131072
#define C 32
#define Zn 10
#define NG 16
#define NB 8
#define H 64
#define TABN 4096
#define TPP 16     // table points per block (16 threads per point)
#define NPB 8      // nodes per node_kernel block (1 wave per node)
#define CAP 64     // bucket capacity per node
#define SL 48      // max edges processed per node

// prep block map
#define TB_TAB  514   // 2 * 257 table blocks (first: longest job)
#define TB_EDGE (TB_TAB + 512)
#define TB_H0   (TB_EDGE + 128)

__device__ __forceinline__ float silu_f(float v){ return v / (1.0f + __expf(-v)); }

// ================================================================ prep (fused):
// [0,514): radial MLP tables, 16 pts/block x 16 thr/pt
// [514,1026): edge filter + bucket snd write
// [1026,1154): species + FULL zero-padded h0 rows (coalesced) + d_out zero
__global__ __launch_bounds__(256)
void prep_kernel(const float* __restrict__ pos, const int* __restrict__ ei,
                 int* __restrict__ cursor, int* __restrict__ bucket,
                 const float* __restrict__ na, const float* __restrict__ Wemb,
                 int* __restrict__ species, float* __restrict__ hg,
                 const float* __restrict__ R0g, const float* __restrict__ R1g,
                 const float* __restrict__ R2g, const float* __restrict__ R3g,
                 float2* __restrict__ Tab2, float* __restrict__ out){
  __shared__ float xsh[TPP*65];
  __shared__ int spec_lds[64];
  int b = blockIdx.x;
  int tid = threadIdx.x;

  if (b >= TB_TAB){
    if (b < TB_EDGE){
      // ---- edge filter + bucket
      int e = (b-TB_TAB)*256 + tid;
      int snd = ei[e], rcv = ei[N_EDGES + e];
      float px = pos[rcv*3+0]-pos[snd*3+0];
      float py = pos[rcv*3+1]-pos[snd*3+1];
      float pz = pos[rcv*3+2]-pos[snd*3+2];
      float r2 = px*px+py*py+pz*pz;
      if (r2 < 25.0f){
        int slot = atomicAdd(cursor + rcv, 1);
        if (slot < CAP) bucket[rcv*CAP + slot] = snd;
      }
    } else {
      // ---- species + full h0 rows (coalesced, zero-padded)
      int n0 = (b-TB_EDGE)*64;
      if (tid < 64){
        int n = n0 + tid;
        int spec = 0;
        #pragma unroll
        for (int z = 1; z < Zn; z++) if (na[n*Zn+z] > 0.5f) spec = z;
        species[n] = spec;
        spec_lds[tid] = spec;
      }
      if (b == TB_EDGE && tid >= 64 && tid < 128) out[tid-64] = 0.f;
      __syncthreads();
      float4* dst = (float4*)(hg + (size_t)n0*288);
      const float4 z4 = make_float4(0.f,0.f,0.f,0.f);
      #pragma unroll
      for (int it = 0; it < 18; it++){
        int f = it*256 + tid;          // [0, 4608) float4s = 64 nodes x 72
        int node = f / 72;
        int q = f - node*72;
        float4 v = z4;
        if (q < 8) v = ((const float4*)(Wemb + spec_lds[node]*C))[q];
        dst[f] = v;
      }
    }
    return;
  }

  // ---- table part: 16 threads per point
  const int nb = 257;                // blocks per half
  int half = (b >= nb) ? 1 : 0;
  int blk  = b - half*nb;
  const float* R0i = R0g + half*NB*H;
  const float* R1i = R1g + half*H*H;
  const float* R2i = R2g + half*H*H;
  const float* R3i = R3g + half*H*96;
  float2* TabH = Tab2 + (size_t)half*((size_t)TABN*96);

  int pl = tid >> 4, jt = tid & 15;
  int i = blk*TPP + pl;
  float r = (i == 0) ? 1e-6f : (float)i * (5.0f/TABN);
  if (jt < 8){
    float xr = r*0.2f;
    float env = 0.f;
    if (xr < 1.0f){
      float x2 = xr*xr, x5 = x2*x2*xr;
      env = 1.f - 21.f*x5 + 35.f*x5*xr - 15.f*x5*x2;
    }
    float sc = 0.6324555320336759f / r * env;
    xsh[pl*65 + jt] = sc * sinf((float)(jt+1)*0.6283185307179586f*r);
  }
  __syncthreads();

  float acc[6];
  // L0: 8 -> 64, 4 cols/thread
  #pragma unroll
  for (int j = 0; j < 4; j++) acc[j] = 0.f;
  #pragma unroll
  for (int k = 0; k < 8; k++){
    float xk = xsh[pl*65 + k];
    float4 w = *(const float4*)(R0i + k*H + jt*4);
    acc[0]=fmaf(xk,w.x,acc[0]); acc[1]=fmaf(xk,w.y,acc[1]);
    acc[2]=fmaf(xk,w.z,acc[2]); acc[3]=fmaf(xk,w.w,acc[3]);
  }
  __syncthreads();
  #pragma unroll
  for (int j = 0; j < 4; j++) xsh[pl*65 + jt*4 + j] = silu_f(acc[j]);
  __syncthreads();

  const float* Wl[2] = {R1i, R2i};
  #pragma unroll
  for (int L = 0; L < 2; L++){
    const float* W = Wl[L];
    #pragma unroll
    for (int j = 0; j < 4; j++) acc[j] = 0.f;
    #pragma unroll 8
    for (int k = 0; k < H; k++){
      float xk = xsh[pl*65 + k];
      float4 w = *(const float4*)(W + k*H + jt*4);
      acc[0]=fmaf(xk,w.x,acc[0]); acc[1]=fmaf(xk,w.y,acc[1]);
      acc[2]=fmaf(xk,w.z,acc[2]); acc[3]=fmaf(xk,w.w,acc[3]);
    }
    __syncthreads();
    #pragma unroll
    for (int j = 0; j < 4; j++) xsh[pl*65 + jt*4 + j] = silu_f(acc[j]);
    __syncthreads();
  }

  // L3: 64 -> 96, 6 cols/thread
  #pragma unroll
  for (int j = 0; j < 6; j++) acc[j] = 0.f;
  #pragma unroll 8
  for (int k = 0; k < H; k++){
    float xk = xsh[pl*65 + k];
    const float* wp = R3i + k*96 + jt*6;
    float2 w0 = *(const float2*)(wp);
    float2 w1 = *(const float2*)(wp+2);
    float2 w2 = *(const float2*)(wp+4);
    acc[0]=fmaf(xk,w0.x,acc[0]); acc[1]=fmaf(xk,w0.y,acc[1]);
    acc[2]=fmaf(xk,w1.x,acc[2]); acc[3]=fmaf(xk,w1.y,acc[3]);
    acc[4]=fmaf(xk,w2.x,acc[4]); acc[5]=fmaf(xk,w2.y,acc[5]);
  }
  if (i <= TABN){
    int cb = jt*6;
    #pragma unroll
    for (int j = 0; j < 6; j++){
      int c = cb + j;
      float val = acc[j];
      if (i < TABN) TabH[(size_t)i*96 + c].x = val;      // lerp lower endpoint
      if (i > 0)    TabH[(size_t)(i-1)*96 + c].y = val;  // lerp upper endpoint
    }
  }
}

// ================================================================ node (EXACT round-10 verified: VGPR 52, 42.7 us):
// lane-parallel edge preamble -> dependency-free gather loop -> slot-wave mix
// (LDS-transposed weights) -> gate -> readout.  1 wave per node, NPB=8.
__global__ __launch_bounds__(512)
void node_kernel(const float2* __restrict__ Tab2, const int* __restrict__ bucket,
                 const int* __restrict__ deg,
                 const float* __restrict__ hg_in, float* __restrict__ hg_out,
                 const float* __restrict__ Wm_g, const float* __restrict__ Ws_g,
                 const float* __restrict__ Wp1, const float* __restrict__ Wp2,
                 const float* __restrict__ Wp3,
                 const int* __restrict__ species, const int* __restrict__ batch,
                 const float* __restrict__ ae, const float* __restrict__ charges,
                 const float* __restrict__ pos,
                 const float* __restrict__ wEv, const float* __restrict__ wDv,
                 const float* __restrict__ Whg, const float* __restrict__ wE2g,
                 int iter, float* __restrict__ out){
  __shared__ float WmT[3*32*34];      // [l][d][c], stride 34
  __shared__ float WsT[3*32*34];
  __shared__ float abuf[NPB][288];    // A (gather) -> A-mixed -> h_new
  __shared__ float sbuf[NPB][288];    // sc
  __shared__ float estage[NPB][SL][6];// per-edge {x,y,z,u,snd}
  __shared__ float glds[NG][4];
  int tid = threadIdx.x;
  for (int t = tid; t < 3072; t += 512){
    int l = t >> 10, rem = t & 1023, c = rem >> 5, d = rem & 31;
    WmT[(l*32+d)*34 + c] = Wm_g[t];
    WsT[(l*32+d)*34 + c] = Ws_g[t];
  }
  if (tid < NG*4) glds[tid>>2][tid&3] = 0.f;
  int w = tid >> 6, lane = tid & 63;
  int c31 = lane & 31;
  bool hi = lane >= 32;
  int ng0 = blockIdx.x*NPB;
  int n = ng0 + w;

  // ---- lane-parallel preamble: stage all edge params (no dependent chains later)
  int cnt = deg[n]; if (cnt > SL) cnt = SL;
  if (lane < cnt){
    int snd = bucket[n*CAP + lane];
    float px = pos[n*3+0] - pos[snd*3+0];
    float py = pos[n*3+1] - pos[snd*3+1];
    float pz = pos[n*3+2] - pos[snd*3+2];
    float r = sqrtf(px*px+py*py+pz*pz + 1e-12f);
    float inv = 1.0f/r;
    float* es = &estage[w][lane][0];
    es[0] = px*inv; es[1] = py*inv; es[2] = pz*inv;
    es[3] = r * (TABN/5.0f);
    es[4] = __int_as_float(snd);
  }

  // ---- gather: only independent loads per edge (3 table + 1 hs)
  const float s3 = 1.7320508075688772f;
  const float s5 = 2.23606797749979f;
  const float s15 = 3.872983346207417f;
  int colA = (hi ? 32 : 0) + c31;    // s=0: m0(l0) / m1(l1)
  int colB = 32 + c31;               // s=1: m2,m3 -> l=1
  int colC = 64 + c31;               // s=2,3,4: l=2
  float acc0=0.f, acc1=0.f, acc2=0.f, acc3=0.f, acc4=0.f;
  #pragma unroll 4
  for (int j = 0; j < cnt; j++){
    const float* es = &estage[w][j][0];
    float x = es[0], y = es[1], z = es[2], u = es[3];
    int snd = __float_as_int(es[4]);
    int i0 = (int)u;
    if (i0 > TABN-1) i0 = TABN-1;
    float f = u - (float)i0;
    const float2* T2 = Tab2 + (size_t)i0*96;
    float hs = hg_in[(size_t)snd*288 + c31];
    float2 ta = T2[colA];
    float2 tb = T2[colB];
    float2 tc = T2[colC];
    float wv0 = fmaf(ta.y - ta.x, f, ta.x) * hs;
    float wv1 = fmaf(tb.y - tb.x, f, tb.x) * hs;
    float wv2 = fmaf(tc.y - tc.x, f, tc.x) * hs;
    float Ys0 = hi ? s3*x : 1.0f;
    float Ys1 = s3 * (hi ? z : y);
    float Ys2 = s15 * (hi ? y*z : x*y);
    float Ys3 = hi ? s15*x*z : 0.5f*s5*(3.f*z*z - 1.f);
    float Ys4 = 0.5f*s15*(x*x - y*y);
    acc0 = fmaf(wv0, Ys0, acc0);
    acc1 = fmaf(wv1, Ys1, acc1);
    acc2 = fmaf(wv2, Ys2, acc2);
    acc3 = fmaf(wv2, Ys3, acc3);
    acc4 = fmaf(wv2, Ys4, acc4);
  }
  abuf[w][lane]       = acc0 * (1.0f/16.0f);
  abuf[w][lane + 64]  = acc1 * (1.0f/16.0f);
  abuf[w][lane + 128] = acc2 * (1.0f/16.0f);
  abuf[w][lane + 192] = acc3 * (1.0f/16.0f);
  if (!hi) abuf[w][lane + 256] = acc4 * (1.0f/16.0f);
  __syncthreads();

  // ---- mix: waves 0..4 each own slot w across the 8 nodes
  float a2[NPB], scv[NPB];
  int idx0 = w*64 + lane;
  bool actm = (w < 5) && (idx0 < 288);
  if (w < 5){
    int m = idx0 >> 5; if (m > 8) m = 8;
    int l = (m >= 4) ? 2 : ((m >= 1) ? 1 : 0);
    const float* wmB = WmT + (l*32 + c31)*34;
    const float* wsB = WsT + (l*32 + c31)*34;
    #pragma unroll
    for (int n2 = 0; n2 < NPB; n2++){ a2[n2] = 0.f; scv[n2] = 0.f; }
    #pragma unroll
    for (int q = 0; q < 8; q++){
      float2 wa0 = *(const float2*)(wmB + 4*q);
      float2 wa1 = *(const float2*)(wmB + 4*q + 2);
      float2 sa0 = *(const float2*)(wsB + 4*q);
      float2 sa1 = *(const float2*)(wsB + 4*q + 2);
      #pragma unroll
      for (int n2 = 0; n2 < NPB; n2++){
        float4 av = *(const float4*)(&abuf[n2][m*32 + 4*q]);
        float4 hv = *(const float4*)(hg_in + (size_t)(ng0+n2)*288 + m*32 + 4*q);
        a2[n2] = fmaf(av.x, wa0.x, a2[n2]); a2[n2] = fmaf(av.y, wa0.y, a2[n2]);
        a2[n2] = fmaf(av.z, wa1.x, a2[n2]); a2[n2] = fmaf(av.w, wa1.y, a2[n2]);
        scv[n2] = fmaf(hv.x, sa0.x, scv[n2]); scv[n2] = fmaf(hv.y, sa0.y, scv[n2]);
        scv[n2] = fmaf(hv.z, sa1.x, scv[n2]); scv[n2] = fmaf(hv.w, sa1.y, scv[n2]);
      }
    }
  }
  __syncthreads();                              // all A reads done
  if (actm){
    #pragma unroll
    for (int n2 = 0; n2 < NPB; n2++){
      abuf[n2][idx0] = a2[n2];
      sbuf[n2][idx0] = scv[n2];
    }
  }
  __syncthreads();

  // ---- gate + h write + readout (wave w = node n)
  int spec = species[n];
  float sval = abuf[w][c31];
  float p1 = Wp1[spec*C+c31], p2 = Wp2[spec*C+c31], p3 = Wp3[spec*C+c31];
  float f = p1 + p2*sval + p3*sval*sval;
  #pragma unroll
  for (int it = 0; it < 5; it++){
    int idx = it*64 + lane;
    if (idx < 288){
      float hn = abuf[w][idx]*f + sbuf[w][idx];
      hg_out[(size_t)n*288 + idx] = hn;
      abuf[w][idx] = hn;
    }
  }

  int g = batch[n];
  float dv0 = 0.f, dv1 = 0.f, dv2 = 0.f, ev = 0.f;
  if (lane < 32){
    dv0 = abuf[w][32+lane]*wDv[lane];
    dv1 = abuf[w][64+lane]*wDv[lane];
    dv2 = abuf[w][96+lane]*wDv[lane];
  }
  if (iter == 0){
    if (lane < 32) ev = abuf[w][lane]*wEv[lane];
  } else {
    if (lane < 16){
      float hid = 0.f;
      #pragma unroll
      for (int c = 0; c < 32; c++) hid = fmaf(abuf[w][c], Whg[c*16+lane], hid);
      hid = silu_f(hid);
      ev = hid * wE2g[lane];
    }
  }
  #pragma unroll
  for (int off = 16; off >= 1; off >>= 1){
    ev  += __shfl_down(ev,  off);
    dv0 += __shfl_down(dv0, off);
    dv1 += __shfl_down(dv1, off);
    dv2 += __shfl_down(dv2, off);
  }
  if (lane == 0){
    if (iter == 0){
      ev += ae[spec];
      float q = charges[n];
      dv0 += q*pos[n*3+0];
      dv1 += q*pos[n*3+1];
      dv2 += q*pos[n*3+2];
    }
    atomicAdd(&glds[g][0], ev);
    atomicAdd(&glds[g][1], dv0);
    atomicAdd(&glds[g][2], dv1);
    atomicAdd(&glds[g][3], dv2);
  }
  __syncthreads();
  if (tid < NG*4){
    float v = glds[tid>>2][tid&3];
    if (v != 0.f) atomicAdd(out + tid, v);
  }
}

// ================================================================ launch
extern "C" void kernel_launch(void* const* d_in, const int* in_sizes, int n_in,
                              void* d_out, int out_size, void* d_ws, size_t ws_size,
                              hipStream_t stream){
  const float* positions       = (const float*)d_in[0];
  const float* node_attrs      = (const float*)d_in[1];
  const float* charges         = (const float*)d_in[2];
  const float* atomic_energies = (const float*)d_in[3];
  const float* W_embed         = (const float*)d_in[4];
  const float* R0              = (const float*)d_in[5];
  const float* R1              = (const float*)d_in[6];
  const float* R2              = (const float*)d_in[7];
  const float* R3              = (const float*)d_in[8];
  const float* W_mix           = (const float*)d_in[9];
  const float* W_sc            = (const float*)d_in[10];
  const float* Wp1             = (const float*)d_in[11];
  const float* Wp2             = (const float*)d_in[12];
  const float* Wp3             = (const float*)d_in[13];
  const float* wE1             = (const float*)d_in[14];
  const float* wD1             = (const float*)d_in[15];
  const float* Wh              = (const float*)d_in[16];
  const float* wE2             = (const float*)d_in[17];
  const float* wD2             = (const float*)d_in[18];
  const int*   edge_index      = (const int*)d_in[19];
  const int*   batch           = (const int*)d_in[20];
  float* out = (float*)d_out;

  char* wsp = (char*)d_ws;
  int*    bucket = (int*)wsp;    wsp += sizeof(int)*(size_t)N_NODES*CAP;
  float2* Tab2   = (float2*)wsp; wsp += sizeof(float2)*(size_t)2*TABN*96;
  float*  hg_a   = (float*)wsp;  wsp += sizeof(float)*(size_t)N_NODES*288;
  float*  hg_b   = (float*)wsp;  wsp += sizeof(float)*(size_t)N_NODES*288;
  int* cursor    = (int*)wsp;    wsp += sizeof(int)*N_NODES;
  int* species   = (int*)wsp;    wsp += sizeof(int)*N_NODES;

  hipMemsetAsync(cursor, 0, N_NODES*sizeof(int), stream);

  prep_kernel<<<TB_H0, 256, 0, stream>>>(positions, edge_index, cursor, bucket,
                                         node_attrs, W_embed, species, hg_a,
                                         R0, R1, R2, R3, Tab2, out);

  for (int i = 0; i < 2; i++){
    const float* hin  = (i == 0) ? hg_a : hg_b;
    float*       hout = (i == 0) ? hg_b : hg_a;
    node_kernel<<<N_NODES/NPB, 512, 0, stream>>>(Tab2 + (size_t)i*TABN*96, bucket,
                                               cursor, hin, hout,
                                               W_mix + i*3*C*C, W_sc + i*3*C*C,
                                               Wp1 + i*Zn*C, Wp2 + i*Zn*C, Wp3 + i*Zn*C,
                                               species, batch,
                                               atomic_energies, charges, positions,
                                               wE1, (i == 0) ? wD1 : wD2,
                                               Wh, wE2, i, out);
  }
}

// Round 17
// 200.374 us; speedup vs baseline: 1.6110x; 1.0077x over previous
//
#include <hip/hip_runtime.h>
#include <math.h>

#define N_NODES 8192
#define N_EDGES 131072
#define C 32
#define Zn 10
#define NG 16
#define NB 8
#define H 64
#define TABN 4096
#define TPP 8      // table points per block (32 threads per point)
#define NPB 8      // nodes per node_kernel block (1 wave per node)
#define CAP 64     // bucket capacity per node
#define SL 48      // max edges processed per node

// prep block map
#define TB_TAB  1026  // 2 * 513 table blocks (first: longest job)
#define TB_EDGE (TB_TAB + 512)
#define TB_H0   (TB_EDGE + 128)

__device__ __forceinline__ float silu_f(float v){ return v / (1.0f + __expf(-v)); }

// ================================================================ prep (fused):
// [0,1026): radial MLP tables, 8 pts/block x 32 thr/pt
// [1026,1538): edge filter + bucket snd write
// [1538,1666): species + FULL zero-padded h0 rows (coalesced) + d_out zero
__global__ __launch_bounds__(256)
void prep_kernel(const float* __restrict__ pos, const int* __restrict__ ei,
                 int* __restrict__ cursor, int* __restrict__ bucket,
                 const float* __restrict__ na, const float* __restrict__ Wemb,
                 int* __restrict__ species, float* __restrict__ hg,
                 const float* __restrict__ R0g, const float* __restrict__ R1g,
                 const float* __restrict__ R2g, const float* __restrict__ R3g,
                 float2* __restrict__ Tab2, float* __restrict__ out){
  __shared__ float xsh[TPP*65];
  __shared__ int spec_lds[64];
  int b = blockIdx.x;
  int tid = threadIdx.x;

  if (b >= TB_TAB){
    if (b < TB_EDGE){
      // ---- edge filter + bucket
      int e = (b-TB_TAB)*256 + tid;
      int snd = ei[e], rcv = ei[N_EDGES + e];
      float px = pos[rcv*3+0]-pos[snd*3+0];
      float py = pos[rcv*3+1]-pos[snd*3+1];
      float pz = pos[rcv*3+2]-pos[snd*3+2];
      float r2 = px*px+py*py+pz*pz;
      if (r2 < 25.0f){
        int slot = atomicAdd(cursor + rcv, 1);
        if (slot < CAP) bucket[rcv*CAP + slot] = snd;
      }
    } else {
      // ---- species + full h0 rows (coalesced, zero-padded)
      int n0 = (b-TB_EDGE)*64;
      if (tid < 64){
        int n = n0 + tid;
        int spec = 0;
        #pragma unroll
        for (int z = 1; z < Zn; z++) if (na[n*Zn+z] > 0.5f) spec = z;
        species[n] = spec;
        spec_lds[tid] = spec;
      }
      if (b == TB_EDGE && tid >= 64 && tid < 128) out[tid-64] = 0.f;
      __syncthreads();
      float4* dst = (float4*)(hg + (size_t)n0*288);
      const float4 z4 = make_float4(0.f,0.f,0.f,0.f);
      #pragma unroll
      for (int it = 0; it < 18; it++){
        int f = it*256 + tid;          // [0, 4608) float4s = 64 nodes x 72
        int node = f / 72;
        int q = f - node*72;
        float4 v = z4;
        if (q < 8) v = ((const float4*)(Wemb + spec_lds[node]*C))[q];
        dst[f] = v;
      }
    }
    return;
  }

  // ---- table part: 32 threads per point, 8 points per block
  const int nb = 513;                // blocks per half
  int half = (b >= nb) ? 1 : 0;
  int blk  = b - half*nb;
  const float* R0i = R0g + half*NB*H;
  const float* R1i = R1g + half*H*H;
  const float* R2i = R2g + half*H*H;
  const float* R3i = R3g + half*H*96;
  float2* TabH = Tab2 + (size_t)half*((size_t)TABN*96);

  int pl = tid >> 5, jt = tid & 31;
  int i = blk*TPP + pl;
  float r = (i == 0) ? 1e-6f : (float)i * (5.0f/TABN);
  if (jt < 8){
    float xr = r*0.2f;
    float env = 0.f;
    if (xr < 1.0f){
      float x2 = xr*xr, x5 = x2*x2*xr;
      env = 1.f - 21.f*x5 + 35.f*x5*xr - 15.f*x5*x2;
    }
    float sc = 0.6324555320336759f / r * env;
    xsh[pl*65 + jt] = sc * sinf((float)(jt+1)*0.6283185307179586f*r);
  }
  __syncthreads();

  float acc[3];
  // L0: 8 -> 64, 2 cols/thread
  acc[0] = 0.f; acc[1] = 0.f;
  #pragma unroll
  for (int k = 0; k < 8; k++){
    float xk = xsh[pl*65 + k];
    float2 w = *(const float2*)(R0i + k*H + jt*2);
    acc[0]=fmaf(xk,w.x,acc[0]); acc[1]=fmaf(xk,w.y,acc[1]);
  }
  __syncthreads();
  xsh[pl*65 + jt*2]     = silu_f(acc[0]);
  xsh[pl*65 + jt*2 + 1] = silu_f(acc[1]);
  __syncthreads();

  const float* Wl[2] = {R1i, R2i};
  #pragma unroll
  for (int L = 0; L < 2; L++){
    const float* W = Wl[L];
    acc[0] = 0.f; acc[1] = 0.f;
    #pragma unroll 8
    for (int k = 0; k < H; k++){
      float xk = xsh[pl*65 + k];
      float2 w = *(const float2*)(W + k*H + jt*2);
      acc[0]=fmaf(xk,w.x,acc[0]); acc[1]=fmaf(xk,w.y,acc[1]);
    }
    __syncthreads();
    xsh[pl*65 + jt*2]     = silu_f(acc[0]);
    xsh[pl*65 + jt*2 + 1] = silu_f(acc[1]);
    __syncthreads();
  }

  // L3: 64 -> 96, 3 cols/thread (scalar loads; jt*3 not float2-aligned)
  acc[0] = 0.f; acc[1] = 0.f; acc[2] = 0.f;
  #pragma unroll 8
  for (int k = 0; k < H; k++){
    float xk = xsh[pl*65 + k];
    const float* wp = R3i + k*96 + jt*3;
    acc[0]=fmaf(xk,wp[0],acc[0]);
    acc[1]=fmaf(xk,wp[1],acc[1]);
    acc[2]=fmaf(xk,wp[2],acc[2]);
  }
  if (i <= TABN){
    int cb = jt*3;
    #pragma unroll
    for (int j = 0; j < 3; j++){
      int c = cb + j;
      float val = acc[j];
      if (i < TABN) TabH[(size_t)i*96 + c].x = val;      // lerp lower endpoint
      if (i > 0)    TabH[(size_t)(i-1)*96 + c].y = val;  // lerp upper endpoint
    }
  }
}

// ================================================================ node (round-10 verified structure: VGPR 52):
// lane-parallel edge preamble -> dependency-free gather loop -> slot-wave mix
// (LDS-transposed weights) -> gate -> readout.  1 wave per node, NPB=8.
// Only delta vs verified: iter-1 skips the dead hg_out store (wave-uniform branch).
__global__ __launch_bounds__(512)
void node_kernel(const float2* __restrict__ Tab2, const int* __restrict__ bucket,
                 const int* __restrict__ deg,
                 const float* __restrict__ hg_in, float* __restrict__ hg_out,
                 const float* __restrict__ Wm_g, const float* __restrict__ Ws_g,
                 const float* __restrict__ Wp1, const float* __restrict__ Wp2,
                 const float* __restrict__ Wp3,
                 const int* __restrict__ species, const int* __restrict__ batch,
                 const float* __restrict__ ae, const float* __restrict__ charges,
                 const float* __restrict__ pos,
                 const float* __restrict__ wEv, const float* __restrict__ wDv,
                 const float* __restrict__ Whg, const float* __restrict__ wE2g,
                 int iter, float* __restrict__ out){
  __shared__ float WmT[3*32*34];      // [l][d][c], stride 34
  __shared__ float WsT[3*32*34];
  __shared__ float abuf[NPB][288];    // A (gather) -> A-mixed -> h_new
  __shared__ float sbuf[NPB][288];    // sc
  __shared__ float estage[NPB][SL][6];// per-edge {x,y,z,u,snd}
  __shared__ float glds[NG][4];
  int tid = threadIdx.x;
  for (int t = tid; t < 3072; t += 512){
    int l = t >> 10, rem = t & 1023, c = rem >> 5, d = rem & 31;
    WmT[(l*32+d)*34 + c] = Wm_g[t];
    WsT[(l*32+d)*34 + c] = Ws_g[t];
  }
  if (tid < NG*4) glds[tid>>2][tid&3] = 0.f;
  int w = tid >> 6, lane = tid & 63;
  int c31 = lane & 31;
  bool hi = lane >= 32;
  int ng0 = blockIdx.x*NPB;
  int n = ng0 + w;

  // ---- lane-parallel preamble: stage all edge params (no dependent chains later)
  int cnt = deg[n]; if (cnt > SL) cnt = SL;
  if (lane < cnt){
    int snd = bucket[n*CAP + lane];
    float px = pos[n*3+0] - pos[snd*3+0];
    float py = pos[n*3+1] - pos[snd*3+1];
    float pz = pos[n*3+2] - pos[snd*3+2];
    float r = sqrtf(px*px+py*py+pz*pz + 1e-12f);
    float inv = 1.0f/r;
    float* es = &estage[w][lane][0];
    es[0] = px*inv; es[1] = py*inv; es[2] = pz*inv;
    es[3] = r * (TABN/5.0f);
    es[4] = __int_as_float(snd);
  }

  // ---- gather: only independent loads per edge (3 table + 1 hs)
  const float s3 = 1.7320508075688772f;
  const float s5 = 2.23606797749979f;
  const float s15 = 3.872983346207417f;
  int colA = (hi ? 32 : 0) + c31;    // s=0: m0(l0) / m1(l1)
  int colB = 32 + c31;               // s=1: m2,m3 -> l=1
  int colC = 64 + c31;               // s=2,3,4: l=2
  float acc0=0.f, acc1=0.f, acc2=0.f, acc3=0.f, acc4=0.f;
  #pragma unroll 4
  for (int j = 0; j < cnt; j++){
    const float* es = &estage[w][j][0];
    float x = es[0], y = es[1], z = es[2], u = es[3];
    int snd = __float_as_int(es[4]);
    int i0 = (int)u;
    if (i0 > TABN-1) i0 = TABN-1;
    float f = u - (float)i0;
    const float2* T2 = Tab2 + (size_t)i0*96;
    float hs = hg_in[(size_t)snd*288 + c31];
    float2 ta = T2[colA];
    float2 tb = T2[colB];
    float2 tc = T2[colC];
    float wv0 = fmaf(ta.y - ta.x, f, ta.x) * hs;
    float wv1 = fmaf(tb.y - tb.x, f, tb.x) * hs;
    float wv2 = fmaf(tc.y - tc.x, f, tc.x) * hs;
    float Ys0 = hi ? s3*x : 1.0f;
    float Ys1 = s3 * (hi ? z : y);
    float Ys2 = s15 * (hi ? y*z : x*y);
    float Ys3 = hi ? s15*x*z : 0.5f*s5*(3.f*z*z - 1.f);
    float Ys4 = 0.5f*s15*(x*x - y*y);
    acc0 = fmaf(wv0, Ys0, acc0);
    acc1 = fmaf(wv1, Ys1, acc1);
    acc2 = fmaf(wv2, Ys2, acc2);
    acc3 = fmaf(wv2, Ys3, acc3);
    acc4 = fmaf(wv2, Ys4, acc4);
  }
  abuf[w][lane]       = acc0 * (1.0f/16.0f);
  abuf[w][lane + 64]  = acc1 * (1.0f/16.0f);
  abuf[w][lane + 128] = acc2 * (1.0f/16.0f);
  abuf[w][lane + 192] = acc3 * (1.0f/16.0f);
  if (!hi) abuf[w][lane + 256] = acc4 * (1.0f/16.0f);
  __syncthreads();

  // ---- mix: waves 0..4 each own slot w across the 8 nodes
  float a2[NPB], scv[NPB];
  int idx0 = w*64 + lane;
  bool actm = (w < 5) && (idx0 < 288);
  if (w < 5){
    int m = idx0 >> 5; if (m > 8) m = 8;
    int l = (m >= 4) ? 2 : ((m >= 1) ? 1 : 0);
    const float* wmB = WmT + (l*32 + c31)*34;
    const float* wsB = WsT + (l*32 + c31)*34;
    #pragma unroll
    for (int n2 = 0; n2 < NPB; n2++){ a2[n2] = 0.f; scv[n2] = 0.f; }
    #pragma unroll
    for (int q = 0; q < 8; q++){
      float2 wa0 = *(const float2*)(wmB + 4*q);
      float2 wa1 = *(const float2*)(wmB + 4*q + 2);
      float2 sa0 = *(const float2*)(wsB + 4*q);
      float2 sa1 = *(const float2*)(wsB + 4*q + 2);
      #pragma unroll
      for (int n2 = 0; n2 < NPB; n2++){
        float4 av = *(const float4*)(&abuf[n2][m*32 + 4*q]);
        float4 hv = *(const float4*)(hg_in + (size_t)(ng0+n2)*288 + m*32 + 4*q);
        a2[n2] = fmaf(av.x, wa0.x, a2[n2]); a2[n2] = fmaf(av.y, wa0.y, a2[n2]);
        a2[n2] = fmaf(av.z, wa1.x, a2[n2]); a2[n2] = fmaf(av.w, wa1.y, a2[n2]);
        scv[n2] = fmaf(hv.x, sa0.x, scv[n2]); scv[n2] = fmaf(hv.y, sa0.y, scv[n2]);
        scv[n2] = fmaf(hv.z, sa1.x, scv[n2]); scv[n2] = fmaf(hv.w, sa1.y, scv[n2]);
      }
    }
  }
  __syncthreads();                              // all A reads done
  if (actm){
    #pragma unroll
    for (int n2 = 0; n2 < NPB; n2++){
      abuf[n2][idx0] = a2[n2];
      sbuf[n2][idx0] = scv[n2];
    }
  }
  __syncthreads();

  // ---- gate + h write + readout (wave w = node n)
  int spec = species[n];
  float sval = abuf[w][c31];
  float p1 = Wp1[spec*C+c31], p2 = Wp2[spec*C+c31], p3 = Wp3[spec*C+c31];
  float f = p1 + p2*sval + p3*sval*sval;
  #pragma unroll
  for (int it = 0; it < 5; it++){
    int idx = it*64 + lane;
    if (idx < 288){
      float hn = abuf[w][idx]*f + sbuf[w][idx];
      if (iter == 0) hg_out[(size_t)n*288 + idx] = hn;   // iter1: h dies here
      abuf[w][idx] = hn;
    }
  }

  int g = batch[n];
  float dv0 = 0.f, dv1 = 0.f, dv2 = 0.f, ev = 0.f;
  if (lane < 32){
    dv0 = abuf[w][32+lane]*wDv[lane];
    dv1 = abuf[w][64+lane]*wDv[lane];
    dv2 = abuf[w][96+lane]*wDv[lane];
  }
  if (iter == 0){
    if (lane < 32) ev = abuf[w][lane]*wEv[lane];
  } else {
    if (lane < 16){
      float hid = 0.f;
      #pragma unroll
      for (int c = 0; c < 32; c++) hid = fmaf(abuf[w][c], Whg[c*16+lane], hid);
      hid = silu_f(hid);
      ev = hid * wE2g[lane];
    }
  }
  #pragma unroll
  for (int off = 16; off >= 1; off >>= 1){
    ev  += __shfl_down(ev,  off);
    dv0 += __shfl_down(dv0, off);
    dv1 += __shfl_down(dv1, off);
    dv2 += __shfl_down(dv2, off);
  }
  if (lane == 0){
    if (iter == 0){
      ev += ae[spec];
      float q = charges[n];
      dv0 += q*pos[n*3+0];
      dv1 += q*pos[n*3+1];
      dv2 += q*pos[n*3+2];
    }
    atomicAdd(&glds[g][0], ev);
    atomicAdd(&glds[g][1], dv0);
    atomicAdd(&glds[g][2], dv1);
    atomicAdd(&glds[g][3], dv2);
  }
  __syncthreads();
  if (tid < NG*4){
    float v = glds[tid>>2][tid&3];
    if (v != 0.f) atomicAdd(out + tid, v);
  }
}

// ================================================================ launch
extern "C" void kernel_launch(void* const* d_in, const int* in_sizes, int n_in,
                              void* d_out, int out_size, void* d_ws, size_t ws_size,
                              hipStream_t stream){
  const float* positions       = (const float*)d_in[0];
  const float* node_attrs      = (const float*)d_in[1];
  const float* charges         = (const float*)d_in[2];
  const float* atomic_energies = (const float*)d_in[3];
  const float* W_embed         = (const float*)d_in[4];
  const float* R0              = (const float*)d_in[5];
  const float* R1              = (const float*)d_in[6];
  const float* R2              = (const float*)d_in[7];
  const float* R3              = (const float*)d_in[8];
  const float* W_mix           = (const float*)d_in[9];
  const float* W_sc            = (const float*)d_in[10];
  const float* Wp1             = (const float*)d_in[11];
  const float* Wp2             = (const float*)d_in[12];
  const float* Wp3             = (const float*)d_in[13];
  const float* wE1             = (const float*)d_in[14];
  const float* wD1             = (const float*)d_in[15];
  const float* Wh              = (const float*)d_in[16];
  const float* wE2             = (const float*)d_in[17];
  const float* wD2             = (const float*)d_in[18];
  const int*   edge_index      = (const int*)d_in[19];
  const int*   batch           = (const int*)d_in[20];
  float* out = (float*)d_out;

  char* wsp = (char*)d_ws;
  int*    bucket = (int*)wsp;    wsp += sizeof(int)*(size_t)N_NODES*CAP;
  float2* Tab2   = (float2*)wsp; wsp += sizeof(float2)*(size_t)2*TABN*96;
  float*  hg_a   = (float*)wsp;  wsp += sizeof(float)*(size_t)N_NODES*288;
  float*  hg_b   = (float*)wsp;  wsp += sizeof(float)*(size_t)N_NODES*288;
  int* cursor    = (int*)wsp;    wsp += sizeof(int)*N_NODES;
  int* species   = (int*)wsp;    wsp += sizeof(int)*N_NODES;

  hipMemsetAsync(cursor, 0, N_NODES*sizeof(int), stream);

  prep_kernel<<<TB_H0, 256, 0, stream>>>(positions, edge_index, cursor, bucket,
                                         node_attrs, W_embed, species, hg_a,
                                         R0, R1, R2, R3, Tab2, out);

  for (int i = 0; i < 2; i++){
    const float* hin  = (i == 0) ? hg_a : hg_b;
    float*       hout = (i == 0) ? hg_b : hg_a;
    node_kernel<<<N_NODES/NPB, 512, 0, stream>>>(Tab2 + (size_t)i*TABN*96, bucket,
                                               cursor, hin, hout,
                                               W_mix + i*3*C*C, W_sc + i*3*C*C,
                                               Wp1 + i*Zn*C, Wp2 + i*Zn*C, Wp3 + i*Zn*C,
                                               species, batch,
                                               atomic_energies, charges, positions,
                                               wE1, (i == 0) ? wD1 : wD2,
                                               Wh, wE2, i, out);
  }
}